// Round 1
// baseline (262.114 us; speedup 1.0000x reference)
//
#include <hip/hip_runtime.h>
#include <math.h>

#define NB 32              // batch
#define HW (1024 * 1024)   // pixels per image
#define BINS 64            // MAX_INST
#define KLBL 64            // labels per image
#define NCLS 8             // lesion classes
#define BPI 64             // blocks per image for histogram
#define TPB 256
#define CHUNK4 4096        // int4 per block chunk (64 KB contiguous)
#define SUBS 4             // sub-histograms per wave (by 16-lane group)

// ---------------------------------------------------------------------------
// Round-6 structure:
//  - Memory path unchanged from round-5 (proven): contiguous 64 KB chunk per
//    block, 8x int4 batched into registers before any LDS traffic.
//  - LDS: 4 sub-histograms per wave, layout sh[wave][bin][sub] with
//    sub=(lane>>4)&3. The *SUBS stride maps each 16-lane group onto a
//    disjoint bank set (bank = (bin*4+sub)%32, groups differ mod 4), cutting
//    same-address atomic serialization 4x and bank max-load to ~2-4.
//  - Finalize fused via last-block-done counter (device-scope atomics);
//    saves one dispatch. hist read back with agent-scope atomic loads so
//    cross-XCD L2 non-coherence cannot serve stale partial sums.
// ---------------------------------------------------------------------------
__global__ __launch_bounds__(TPB) void hist_fused_kernel(
        const float* __restrict__ pred,
        const int*   __restrict__ mask,
        const int*   __restrict__ lg,
        int*         __restrict__ hist,
        int*         __restrict__ done_cnt,
        float*       __restrict__ out) {
    __shared__ int sh[4][BINS][SUBS];   // 4 KB
    const int tid  = threadIdx.x;
    const int b    = blockIdx.x / BPI;
    const int part = blockIdx.x % BPI;
    const int wave = tid >> 6;
    const int sub  = (tid >> 4) & (SUBS - 1);

    #pragma unroll
    for (int i = 0; i < (4 * BINS * SUBS) / TPB; ++i)
        ((int*)sh)[i * TPB + tid] = 0;
    __syncthreads();

    const int4* __restrict__ p4 =
        (const int4*)(mask + (size_t)b * HW) + (size_t)part * CHUNK4;

    #pragma unroll
    for (int h = 0; h < 2; ++h) {
        int4 v[8];
        #pragma unroll
        for (int k = 0; k < 8; ++k)
            v[k] = p4[(h * 8 + k) * TPB + tid];   // wave req k: 4 KB apart, dense
        #pragma unroll
        for (int k = 0; k < 8; ++k) {
            atomicAdd(&sh[wave][v[k].x & 63][sub], 1);
            atomicAdd(&sh[wave][v[k].y & 63][sub], 1);
            atomicAdd(&sh[wave][v[k].z & 63][sub], 1);
            atomicAdd(&sh[wave][v[k].w & 63][sub], 1);
        }
    }
    __syncthreads();

    if (tid < BINS) {
        int s = 0;
        #pragma unroll
        for (int w = 0; w < 4; ++w)
            #pragma unroll
            for (int q = 0; q < SUBS; ++q)
                s += sh[w][tid][q];
        atomicAdd(&hist[b * BINS + tid], s);
    }
    __syncthreads();   // barrier drains vmcnt: this block's global atomics complete

    __shared__ int isLast;
    if (tid == 0) {
        __threadfence();
        isLast = (atomicAdd(done_cnt, 1) == (NB * BPI) - 1);
    }
    __syncthreads();
    if (!isLast) return;       // block-uniform: whole block exits together
    __threadfence();

    // ---- finalize (last block only): gather sizes, per-class scatter,
    //      clamp/100, BCE-with-logits, mean -> out[0] ----
    __shared__ float cnts[NB * NCLS];
    __shared__ float wsum[4];
    cnts[tid] = 0.0f;
    __syncthreads();

    for (int e = tid; e < NB * KLBL; e += TPB) {
        int inst  = lg[e * 2 + 0];
        int label = lg[e * 2 + 1];
        if (label > 0 && label <= NCLS) {
            int szi = __hip_atomic_load(&hist[(e >> 6) * BINS + (inst & 63)],
                                        __ATOMIC_RELAXED, __HIP_MEMORY_SCOPE_AGENT);
            atomicAdd(&cnts[(e >> 6) * NCLS + (label - 1)], (float)szi);
        }
    }
    __syncthreads();

    float x = pred[tid];
    float t = fminf(cnts[tid] * (1.0f / 100.0f), 1.0f);
    float l = fmaxf(x, 0.0f) - x * t + log1pf(expf(-fabsf(x)));

    for (int off = 32; off > 0; off >>= 1)
        l += __shfl_down(l, off, 64);
    if ((tid & 63) == 0) wsum[tid >> 6] = l;
    __syncthreads();
    if (tid == 0)
        out[0] = (wsum[0] + wsum[1] + wsum[2] + wsum[3]) * (1.0f / (NB * NCLS));
}

extern "C" void kernel_launch(void* const* d_in, const int* in_sizes, int n_in,
                              void* d_out, int out_size, void* d_ws, size_t ws_size,
                              hipStream_t stream) {
    const float* pred = (const float*)d_in[0];    // [32, 8] fp32
    const int*   mask = (const int*)d_in[1];      // [32, 1024, 1024] int32
    const int*   lg   = (const int*)d_in[2];      // [32, 64, 2] delivered as int32
    float* out = (float*)d_out;
    int* hist = (int*)d_ws;                       // [32][64] int32 = 8 KB
    int* done = hist + NB * BINS;                 // completion counter

    hipMemsetAsync(d_ws, 0, (NB * BINS + 1) * sizeof(int), stream);
    hist_fused_kernel<<<NB * BPI, TPB, 0, stream>>>(pred, mask, lg, hist, done, out);
}

// Round 2
// 207.959 us; speedup vs baseline: 1.2604x; 1.2604x over previous
//
#include <hip/hip_runtime.h>
#include <math.h>

#define NB 32              // batch
#define HW (1024 * 1024)   // pixels per image
#define BINS 64            // MAX_INST
#define KLBL 64            // labels per image
#define NCLS 8             // lesion classes
#define BPI 64             // blocks per image for histogram
#define TPB 256
#define CHUNK4 4096        // int4 per block chunk (64 KB contiguous)
#define WORDS 32           // 64 bins packed 2 x u16 per dword

// ---------------------------------------------------------------------------
// Round-7 structure:
//  - REVERTED the round-6 fusion (device-fence + single-address done counter
//    regressed; finalize is a separate tiny kernel again).
//  - NO LDS ATOMICS: per-thread privatized histogram, 64 bins packed as
//    2 x u16 into 32 dwords, layout priv[word][tid] -> bank = tid % 32:
//    every lane hits its own bank (lane L / L+32 share a bank at different
//    addresses = free 2-way). Inner loop is plain read/add/write, no RMW
//    serialization. Max count/thread/bin = 64 <= u16; block total per bin
//    <= 16384 so packed u32 adds never carry across halves.
//  - MLP forced: all 16 int4 loaded into registers, then
//    sched_barrier(0) pins them BEFORE any LDS traffic (round-6 showed the
//    compiler otherwise fuses load+use and drops to VGPR=12, serializing).
// ---------------------------------------------------------------------------
__global__ __launch_bounds__(TPB) void hist_kernel(const int* __restrict__ mask,
                                                   int* __restrict__ hist) {
    __shared__ unsigned int priv[WORDS][TPB];   // 32 KB
    const int tid = threadIdx.x;
    const int b = blockIdx.x / BPI;
    const int part = blockIdx.x % BPI;

    {   // zero 32*256 dwords: 8 x uint4 per thread
        uint4* z = (uint4*)&priv[0][0];
        #pragma unroll
        for (int i = 0; i < 8; ++i)
            z[i * TPB + tid] = make_uint4(0u, 0u, 0u, 0u);
    }
    __syncthreads();

    const int4* __restrict__ p4 =
        (const int4*)(mask + (size_t)b * HW) + (size_t)part * CHUNK4;

    int4 v[16];
    #pragma unroll
    for (int k = 0; k < 16; ++k)
        v[k] = p4[k * TPB + tid];        // wave req k: 4 KB apart, dense walk
    __builtin_amdgcn_sched_barrier(0);   // all 16 dwordx4 in flight first

    #pragma unroll
    for (int k = 0; k < 16; ++k) {
        int vals[4] = {v[k].x, v[k].y, v[k].z, v[k].w};
        #pragma unroll
        for (int j = 0; j < 4; ++j) {
            int q = vals[j] & 63;
            priv[q >> 1][tid] += 1u << ((q & 1) << 4);   // own bank, no atomic
        }
    }
    __syncthreads();

    // Reduce: thread -> word w = tid>>3, slice p = tid&7 sums 32 dwords
    // (8 x uint4), packed halves can't carry; then 8-lane shfl tree.
    const int w = tid >> 3, p = tid & 7;
    unsigned int s = 0;
    #pragma unroll
    for (int j = 0; j < 8; ++j) {
        uint4 r = *(const uint4*)&priv[w][p * 32 + j * 4];
        s += r.x + r.y + r.z + r.w;
    }
    #pragma unroll
    for (int off = 4; off > 0; off >>= 1)
        s += __shfl_down(s, off, 8);
    if (p == 0) {
        atomicAdd(&hist[b * BINS + 2 * w],     (int)(s & 0xFFFFu));
        atomicAdd(&hist[b * BINS + 2 * w + 1], (int)(s >> 16));
    }
}

// ---------------------------------------------------------------------------
// Finalize (known-good round-5 version): gather sizes via label_gt, scatter
// into per-class counts, clamp/100, BCE-with-logits, mean -> out[0].
// ---------------------------------------------------------------------------
__global__ __launch_bounds__(TPB) void finalize_kernel(const float* __restrict__ pred,
                                                       const int* __restrict__ lg,
                                                       const int* __restrict__ hist,
                                                       float* __restrict__ out) {
    __shared__ float cnts[NB * NCLS];
    __shared__ float wsum[4];
    const int tid = threadIdx.x;

    cnts[tid] = 0.0f;
    __syncthreads();

    for (int e = tid; e < NB * KLBL; e += TPB) {
        int inst  = lg[e * 2 + 0];
        int label = lg[e * 2 + 1];
        if (label > 0 && label <= NCLS) {
            float sz = (float)hist[(e >> 6) * BINS + (inst & 63)];
            atomicAdd(&cnts[(e >> 6) * NCLS + (label - 1)], sz);
        }
    }
    __syncthreads();

    float x = pred[tid];
    float t = fminf(cnts[tid] * (1.0f / 100.0f), 1.0f);
    float l = fmaxf(x, 0.0f) - x * t + log1pf(expf(-fabsf(x)));

    for (int off = 32; off > 0; off >>= 1)
        l += __shfl_down(l, off, 64);
    if ((tid & 63) == 0) wsum[tid >> 6] = l;
    __syncthreads();
    if (tid == 0)
        out[0] = (wsum[0] + wsum[1] + wsum[2] + wsum[3]) * (1.0f / (NB * NCLS));
}

extern "C" void kernel_launch(void* const* d_in, const int* in_sizes, int n_in,
                              void* d_out, int out_size, void* d_ws, size_t ws_size,
                              hipStream_t stream) {
    const float* pred = (const float*)d_in[0];    // [32, 8] fp32
    const int*   mask = (const int*)d_in[1];      // [32, 1024, 1024] int32
    const int*   lg   = (const int*)d_in[2];      // [32, 64, 2] delivered as int32
    float* out = (float*)d_out;
    int* hist = (int*)d_ws;                       // [32][64] int32 = 8 KB

    hipMemsetAsync(hist, 0, NB * BINS * sizeof(int), stream);
    hist_kernel<<<NB * BPI, TPB, 0, stream>>>(mask, hist);
    finalize_kernel<<<1, TPB, 0, stream>>>(pred, lg, hist, out);
}

// Round 3
// 207.327 us; speedup vs baseline: 1.2643x; 1.0030x over previous
//
#include <hip/hip_runtime.h>
#include <math.h>

#define NB 32              // batch
#define HW (1024 * 1024)   // pixels per image
#define BINS 64            // MAX_INST
#define KLBL 64            // labels per image
#define NCLS 8             // lesion classes
#define TPB 256            // 4 waves
#define BPI 32             // blocks per image (persistent)
#define NBLK (NB * BPI)    // 1024 = 4 blocks/CU exactly, single generation
#define STAGES 8           // 8 x 16KB stages = 128 KB region per block
#define STG_I4 1024        // int4 per stage per block (16 KB)
#define WAVE_I4 256        // int4 per stage per wave (4 KB)
#define SUBS 4

// ---------------------------------------------------------------------------
// Round-8 theory: rounds 5 and 7 tie (~45 us hist) despite opposite LDS
// strategies => limiter is memory-level parallelism, not LDS. Reg-staged
// loads cap at ~4 KB in flight per CU (VGPR-bounded) => ~1 MB device-wide
// vs the 2.6 MB (BW x latency) needed for 6.9 TB/s => observed ~2.8 TB/s.
// Fix: global_load_lds DMA (no VGPR cost), double-buffered 2x16KB staging
// per block => >=32 KB/CU in flight, HBM-saturated.
//  - Each wave DMAs and consumes ONLY its own 4 KB sub-chunk: no
//    __syncthreads in the loop, per-wave counted s_waitcnt vmcnt(4).
//  - Wave-private hist sh[wave][bin][sub4]: 16-lane groups on disjoint
//    bank sets; LDS pipe ~13 us/CU hides under ~20 us memory.
//  - Per-block partial hist to global (no atomics, no memset dispatch).
// ---------------------------------------------------------------------------
__global__ __launch_bounds__(TPB) void hist_kernel(const int* __restrict__ mask,
                                                   int* __restrict__ part) {
    __shared__ int4 stage[2][STG_I4];            // 32 KB staging
    __shared__ unsigned int sh[4][BINS][SUBS];   // 4 KB histograms
    const int tid  = threadIdx.x;
    const int wave = tid >> 6;
    const int lane = tid & 63;
    const int sub  = (tid >> 4) & (SUBS - 1);

    // zero hist: 256 uint4 = 4 KB; uint4 index tid>>6 region == own wave's
    // sh[wave] block, so no barrier needed (wave-private throughout).
    ((uint4*)sh)[tid] = make_uint4(0u, 0u, 0u, 0u);

    const int b = blockIdx.x >> 5;
    const int r = blockIdx.x & 31;
    const int4* gbase = (const int4*)(mask + (size_t)b * HW)
                      + (size_t)r * (STAGES * STG_I4);

    // Issue one stage's 4 KB for this wave: 4 x global_load_lds_dwordx4,
    // per-lane global addr, wave-uniform LDS dest (HW adds lane*16).
    auto issue = [&](int buf, int s) {
        const int4* gp = gbase + s * STG_I4 + wave * WAVE_I4 + lane;
        int4* lp = &stage[buf][wave * WAVE_I4];
        #pragma unroll
        for (int k = 0; k < 4; ++k)
            __builtin_amdgcn_global_load_lds(
                (const __attribute__((address_space(1))) void*)(gp + k * 64),
                (__attribute__((address_space(3))) void*)(lp + k * 64),
                16, 0, 0);
    };

    issue(0, 0);
    for (int s = 0; s < STAGES; ++s) {
        const int buf = s & 1;
        if (s + 1 < STAGES) {
            issue(buf ^ 1, s + 1);                       // keep 8 in flight
            asm volatile("s_waitcnt vmcnt(4)" ::: "memory");  // stage s landed
        } else {
            asm volatile("s_waitcnt vmcnt(0)" ::: "memory");
        }
        __builtin_amdgcn_sched_barrier(0);

        int4 v[4];
        #pragma unroll
        for (int j = 0; j < 4; ++j)
            v[j] = stage[buf][wave * WAVE_I4 + j * 64 + lane];
        #pragma unroll
        for (int j = 0; j < 4; ++j) {
            atomicAdd(&sh[wave][v[j].x & 63][sub], 1u);
            atomicAdd(&sh[wave][v[j].y & 63][sub], 1u);
            atomicAdd(&sh[wave][v[j].z & 63][sub], 1u);
            atomicAdd(&sh[wave][v[j].w & 63][sub], 1u);
        }
    }
    __syncthreads();

    if (tid < BINS) {
        unsigned int s = 0;
        #pragma unroll
        for (int w = 0; w < 4; ++w)
            #pragma unroll
            for (int q = 0; q < SUBS; ++q)
                s += sh[w][tid][q];
        part[blockIdx.x * BINS + tid] = (int)s;   // private slot, no atomic
    }
}

// ---------------------------------------------------------------------------
// Finalize: reduce 1024x64 partials (256 KB) -> hist in LDS, then gather via
// label_gt, per-class scatter, clamp/100, BCE-with-logits, mean -> out[0].
// ---------------------------------------------------------------------------
__global__ __launch_bounds__(TPB) void finalize_kernel(const float* __restrict__ pred,
                                                       const int* __restrict__ lg,
                                                       const int* __restrict__ part,
                                                       float* __restrict__ out) {
    __shared__ int hist[NB][BINS];    // 8 KB
    __shared__ float cnts[NB * NCLS];
    __shared__ float wsum[4];
    const int tid = threadIdx.x;

    // thread t: image b = t>>3, bins bg*8..bg*8+7; sum 32 block-partials
    const int b = tid >> 3, bg = tid & 7;
    int4 a0 = make_int4(0, 0, 0, 0), a1 = make_int4(0, 0, 0, 0);
    #pragma unroll 4
    for (int blk = 0; blk < BPI; ++blk) {
        const int* row = part + (b * BPI + blk) * BINS + bg * 8;
        int4 r0 = *(const int4*)(row);
        int4 r1 = *(const int4*)(row + 4);
        a0.x += r0.x; a0.y += r0.y; a0.z += r0.z; a0.w += r0.w;
        a1.x += r1.x; a1.y += r1.y; a1.z += r1.z; a1.w += r1.w;
    }
    *(int4*)&hist[b][bg * 8]     = a0;
    *(int4*)&hist[b][bg * 8 + 4] = a1;

    cnts[tid] = 0.0f;
    __syncthreads();

    for (int e = tid; e < NB * KLBL; e += TPB) {
        int inst  = lg[e * 2 + 0];
        int label = lg[e * 2 + 1];
        if (label > 0 && label <= NCLS) {
            float sz = (float)hist[e >> 6][inst & 63];
            atomicAdd(&cnts[(e >> 6) * NCLS + (label - 1)], sz);
        }
    }
    __syncthreads();

    float x = pred[tid];
    float t = fminf(cnts[tid] * (1.0f / 100.0f), 1.0f);
    float l = fmaxf(x, 0.0f) - x * t + log1pf(expf(-fabsf(x)));

    for (int off = 32; off > 0; off >>= 1)
        l += __shfl_down(l, off, 64);
    if ((tid & 63) == 0) wsum[tid >> 6] = l;
    __syncthreads();
    if (tid == 0)
        out[0] = (wsum[0] + wsum[1] + wsum[2] + wsum[3]) * (1.0f / (NB * NCLS));
}

extern "C" void kernel_launch(void* const* d_in, const int* in_sizes, int n_in,
                              void* d_out, int out_size, void* d_ws, size_t ws_size,
                              hipStream_t stream) {
    const float* pred = (const float*)d_in[0];    // [32, 8] fp32
    const int*   mask = (const int*)d_in[1];      // [32, 1024, 1024] int32
    const int*   lg   = (const int*)d_in[2];      // [32, 64, 2] delivered as int32
    float* out = (float*)d_out;
    int* part = (int*)d_ws;                       // [1024][64] int32 = 256 KB
    // every partial slot is fully overwritten each launch -> no memset needed

    hist_kernel<<<NBLK, TPB, 0, stream>>>(mask, part);
    finalize_kernel<<<1, TPB, 0, stream>>>(pred, lg, part, out);
}

// Round 4
// 201.980 us; speedup vs baseline: 1.2977x; 1.0265x over previous
//
#include <hip/hip_runtime.h>
#include <math.h>

#define NB 32              // batch
#define HW (1024 * 1024)   // pixels per image
#define BINS 64            // MAX_INST
#define KLBL 64            // labels per image
#define NCLS 8             // lesion classes
#define TPB 256            // 4 waves
#define BPI 32             // blocks per image
#define NBLK (NB * BPI)    // 1024 = 4 blocks/CU exactly, single generation
#define STG 64             // int4 per wave-stage (1 KB = one global_load_lds_dwordx4)
#define NST 32             // stages per wave (32 KB region per wave)
#define DEPTH 4            // wave-stages in flight

// ---------------------------------------------------------------------------
// Round-9 model (fits r5/r7/r8 all landing ~204-208):
//   ds_atomic_add is ~25-35 cyc/instr (multi-pass RMW), so r8's 4 atomics per
//   int4 put the LDS pipe at ~29 us/CU > 19.5 us memory floor: DMA fixed MLP
//   but the kernel flipped to LDS-atomic-bound at the same duration.
// Fix both legs at once:
//  - Keep global_load_lds DMA (depth-4 per wave, wave-private free-running,
//    no barriers in the main loop) -> memory saturated without VGPR cost.
//  - PAIR-KEY histogram: table[(v1<<6)|v2]++ over a 4096-entry LDS table.
//    Halves atomic instrs (2 per int4) AND spreads 64 lanes over 4096 keys
//    (collisions ~1%, banks ~uniform) -> LDS pipe ~11 us/CU, hidden again.
//  - Fold table -> 64 bins once per block (row-sums = first-of-pair bin,
//    col-sums = second-of-pair bin), then global atomic hist (8 KB).
//  - r8 bug fixed: wait -> consume -> issue ordering (issue(s+4) writes
//    buf s&3, so issuing before consuming raced the DMA against ds_read).
//  - Finalize reverted to proven 8 KB-read version (r8's 256 KB partials
//    read cost ~5 us on one block).
// ---------------------------------------------------------------------------
__global__ __launch_bounds__(TPB) void hist_kernel(const int* __restrict__ mask,
                                                   int* __restrict__ hist) {
    __shared__ int4 stage[DEPTH][4][STG];        // 16 KB staging
    __shared__ unsigned int table[BINS * BINS];  // 16 KB pair-table
    __shared__ unsigned int h64[BINS];

    const int tid = threadIdx.x;
    const int wave = tid >> 6, lane = tid & 63;

    {   // zero table (1024 uint4) + h64
        uint4* z = (uint4*)table;
        #pragma unroll
        for (int i = 0; i < (BINS * BINS / 4) / TPB; ++i)
            z[i * TPB + tid] = make_uint4(0u, 0u, 0u, 0u);
        if (tid < BINS) h64[tid] = 0u;
    }
    __syncthreads();

    const int b = blockIdx.x >> 5, r = blockIdx.x & 31;
    const int4* gw = (const int4*)(mask + (size_t)b * HW)
                   + (size_t)r * (4 * NST * STG) + wave * (NST * STG) + lane;

    auto issue = [&](int s) {   // one dwordx4 DMA: 64 lanes x 16 B = 1 KB stage
        __builtin_amdgcn_global_load_lds(
            (const __attribute__((address_space(1))) void*)(gw + s * STG),
            (__attribute__((address_space(3))) void*)&stage[s & (DEPTH - 1)][wave][0],
            16, 0, 0);
    };
    auto consume = [&](int s) {
        int4 v = stage[s & (DEPTH - 1)][wave][lane];
        atomicAdd(&table[((v.x & 63) << 6) | (v.y & 63)], 1u);
        atomicAdd(&table[((v.z & 63) << 6) | (v.w & 63)], 1u);
    };

    #pragma unroll
    for (int k = 0; k < DEPTH; ++k) issue(k);

    #pragma unroll 4
    for (int s = 0; s < NST - DEPTH; ++s) {
        asm volatile("s_waitcnt vmcnt(3)" ::: "memory");   // stage s landed
        __builtin_amdgcn_sched_barrier(0);
        consume(s);
        issue(s + DEPTH);                                  // refill same buf AFTER read
    }
    asm volatile("s_waitcnt vmcnt(0)" ::: "memory");
    __builtin_amdgcn_sched_barrier(0);
    #pragma unroll
    for (int s = NST - DEPTH; s < NST; ++s) consume(s);

    __syncthreads();

    // Fold 64x64 table: row r -> bin r (first of pair), col c -> bin c (second).
    // Thread t: row/col index tid>>2, 16-element slice (tid&3)*16.
    unsigned int acc = 0;
    {
        const uint4* tr = (const uint4*)&table[(tid >> 2) * BINS + (tid & 3) * 16];
        #pragma unroll
        for (int j = 0; j < 4; ++j) { uint4 u = tr[j]; acc += u.x + u.y + u.z + u.w; }
        #pragma unroll
        for (int j = 0; j < 16; ++j)
            acc += table[((tid & 3) * 16 + j) * BINS + (tid >> 2)];
    }
    atomicAdd(&h64[tid >> 2], acc);
    __syncthreads();
    if (tid < BINS) atomicAdd(&hist[b * BINS + tid], (int)h64[tid]);
}

// ---------------------------------------------------------------------------
// Finalize (proven round-5 version): gather sizes via label_gt, scatter into
// per-class counts, clamp/100, BCE-with-logits, mean -> out[0].
// ---------------------------------------------------------------------------
__global__ __launch_bounds__(TPB) void finalize_kernel(const float* __restrict__ pred,
                                                       const int* __restrict__ lg,
                                                       const int* __restrict__ hist,
                                                       float* __restrict__ out) {
    __shared__ float cnts[NB * NCLS];
    __shared__ float wsum[4];
    const int tid = threadIdx.x;

    cnts[tid] = 0.0f;
    __syncthreads();

    for (int e = tid; e < NB * KLBL; e += TPB) {
        int inst  = lg[e * 2 + 0];
        int label = lg[e * 2 + 1];
        if (label > 0 && label <= NCLS) {
            float sz = (float)hist[(e >> 6) * BINS + (inst & 63)];
            atomicAdd(&cnts[(e >> 6) * NCLS + (label - 1)], sz);
        }
    }
    __syncthreads();

    float x = pred[tid];
    float t = fminf(cnts[tid] * (1.0f / 100.0f), 1.0f);
    float l = fmaxf(x, 0.0f) - x * t + log1pf(expf(-fabsf(x)));

    for (int off = 32; off > 0; off >>= 1)
        l += __shfl_down(l, off, 64);
    if ((tid & 63) == 0) wsum[tid >> 6] = l;
    __syncthreads();
    if (tid == 0)
        out[0] = (wsum[0] + wsum[1] + wsum[2] + wsum[3]) * (1.0f / (NB * NCLS));
}

extern "C" void kernel_launch(void* const* d_in, const int* in_sizes, int n_in,
                              void* d_out, int out_size, void* d_ws, size_t ws_size,
                              hipStream_t stream) {
    const float* pred = (const float*)d_in[0];    // [32, 8] fp32
    const int*   mask = (const int*)d_in[1];      // [32, 1024, 1024] int32
    const int*   lg   = (const int*)d_in[2];      // [32, 64, 2] delivered as int32
    float* out = (float*)d_out;
    int* hist = (int*)d_ws;                       // [32][64] int32 = 8 KB

    hipMemsetAsync(hist, 0, NB * BINS * sizeof(int), stream);
    hist_kernel<<<NBLK, TPB, 0, stream>>>(mask, hist);
    finalize_kernel<<<1, TPB, 0, stream>>>(pred, lg, hist, out);
}